// Round 1
// baseline (27.128 us; speedup 1.0000x reference)
//
#include <hip/hip_runtime.h>
#include <math.h>

// Problem constants (match reference)
#define IMG_H 512
#define IMG_W 512
#define PIX   (IMG_H * IMG_W)        // 262144 pixels per batch
#define BPB   32                     // blocks per batch
#define THREADS 256
#define CHUNK (PIX / BPB)            // 8192 floats per block
#define VEC_ITERS (CHUNK / (THREADS * 4))  // 8 float4 loads per thread

#define MAX_DIST_F 724.07734394f     // sqrt(512^2 + 512^2)
#define EPS_F 1e-6f

// Per-block partial reduction: sp = sum(p), spd = sum(p*d), spw = sum((wd+eps)^-9)
__global__ __launch_bounds__(THREADS) void whd_partial_kernel(
    const float* __restrict__ prob,      // (B, 512, 512)
    const float* __restrict__ gt,        // (B, 2) (y, x)
    const float* __restrict__ orig,      // (B, 2) (h, w)
    double* __restrict__ ws)             // (B*BPB, 3) partials
{
    const int blk = blockIdx.x;
    const int b   = blk / BPB;
    const int sub = blk % BPB;
    const int t   = threadIdx.x;

    // Per-batch scalars (broadcast loads, L1/L2 hits)
    const float norm_y = orig[2 * b + 0] * (1.0f / IMG_H);
    const float norm_x = orig[2 * b + 1] * (1.0f / IMG_W);
    const float gy = gt[2 * b + 0] * norm_y;
    const float gx = gt[2 * b + 1] * norm_x;

    const float* pbase = prob + (size_t)b * PIX + (size_t)sub * CHUNK;
    const int pix0 = sub * CHUNK;

    float sp = 0.0f, spd = 0.0f, spw = 0.0f;

#pragma unroll
    for (int j = 0; j < VEC_ITERS; ++j) {
        const int off = (j * THREADS + t) * 4;     // float offset within chunk
        const float4 pv = *reinterpret_cast<const float4*>(pbase + off);
        const int i0 = pix0 + off;                 // global pixel index of pv.x
#pragma unroll
        for (int k = 0; k < 4; ++k) {
            const float p = (&pv.x)[k];
            const int ii = i0 + k;
            const float y = (float)(ii >> 9);      // W == 512
            const float x = (float)(ii & 511);
            const float dy = y * norm_y - gy;
            const float dx = x * norm_x - gx;
            const float d = sqrtf(dy * dy + dx * dx);
            sp  += p;
            spd += p * d;
            // weighted_d + EPS, then ^-9 via reciprocal-first (avoids f32 underflow)
            const float wd = (1.0f - p) * MAX_DIST_F + p * d + EPS_F;
            const float r  = 1.0f / wd;
            const float r2 = r * r;
            const float r4 = r2 * r2;
            const float r8 = r4 * r4;
            spw += r8 * r;
        }
    }

    // Block reduction in double: wave shuffle (64 lanes) then LDS across 4 waves
    double v0 = (double)sp, v1 = (double)spd, v2 = (double)spw;
#pragma unroll
    for (int o = 32; o > 0; o >>= 1) {
        v0 += __shfl_down(v0, o, 64);
        v1 += __shfl_down(v1, o, 64);
        v2 += __shfl_down(v2, o, 64);
    }
    __shared__ double red[3][THREADS / 64];
    const int wave = t >> 6;
    const int lane = t & 63;
    if (lane == 0) {
        red[0][wave] = v0;
        red[1][wave] = v1;
        red[2][wave] = v2;
    }
    __syncthreads();
    if (t == 0) {
        double s0 = 0.0, s1 = 0.0, s2 = 0.0;
#pragma unroll
        for (int wv = 0; wv < THREADS / 64; ++wv) {
            s0 += red[0][wv];
            s1 += red[1][wv];
            s2 += red[2][wv];
        }
        double* w = ws + (size_t)blk * 3;
        w[0] = s0;
        w[1] = s1;
        w[2] = s2;
    }
}

// Fold BPB partials per batch, finalize terms. One block, B threads.
__global__ void whd_final_kernel(const double* __restrict__ ws,
                                 float* __restrict__ out, int B)
{
    const int b = threadIdx.x;
    if (b >= B) return;
    double sp = 0.0, spd = 0.0, spw = 0.0;
    for (int s = 0; s < BPB; ++s) {
        const double* w = ws + (size_t)(b * BPB + s) * 3;
        sp  += w[0];
        spd += w[1];
        spw += w[2];
    }
    const double term1 = spd / (sp + 1e-6);
    const double mean  = spw / (double)PIX;
    const double term2 = pow(mean, -1.0 / 9.0);   // mean ** (1/P_EXP), P_EXP = -9
    out[b] = (float)(term1 + term2);
}

extern "C" void kernel_launch(void* const* d_in, const int* in_sizes, int n_in,
                              void* d_out, int out_size, void* d_ws, size_t ws_size,
                              hipStream_t stream) {
    const float* prob = (const float*)d_in[0];
    const float* gt   = (const float*)d_in[1];
    const float* orig = (const float*)d_in[2];
    float* out = (float*)d_out;
    double* ws = (double*)d_ws;

    const int B = in_sizes[0] / PIX;   // 64

    whd_partial_kernel<<<B * BPB, THREADS, 0, stream>>>(prob, gt, orig, ws);
    whd_final_kernel<<<1, ((B + 63) / 64) * 64, 0, stream>>>(ws, out, B);
}